// Round 2
// baseline (134.314 us; speedup 1.0000x reference)
//
#include <hip/hip_runtime.h>

typedef __bf16 bf16x8 __attribute__((ext_vector_type(8)));
typedef float f32x4 __attribute__((ext_vector_type(4)));
typedef float f32x2 __attribute__((ext_vector_type(2)));

#define TB 256
#define GROUPS 8
#define PTS_PER_BLOCK 512   // 4 waves * 8 groups * 16 pts

// round-to-nearest-even float -> bf16 bits (low 16)
__device__ __forceinline__ unsigned int bf16rn(float f) {
  unsigned int u = __float_as_uint(f);
  return (u + 0x7fffu + ((u >> 16) & 1u)) >> 16;
}
__device__ __forceinline__ unsigned int pk2rn(float a, float b) {
  return bf16rn(a) | (bf16rn(b) << 16);
}
__device__ __forceinline__ f32x2 unpk(unsigned int u) {
  f32x2 r;
  r.x = __uint_as_float(u << 16);
  r.y = __uint_as_float(u & 0xffff0000u);
  return r;
}
// v_add with DPP row_shr:N (reduction within each 16-lane row, result in lane 15)
template <int CTRL>
__device__ __forceinline__ float dpp_add(float v) {
  return v + __int_as_float(
                 __builtin_amdgcn_update_dpp(0, __float_as_int(v), CTRL, 0xf, 0xf, true));
}

__global__ __launch_bounds__(TB, 5) void fused_kernel(
    const float* __restrict__ coords, const float* __restrict__ lines,
    const float* __restrict__ W1, const float* __restrict__ b1,
    const float* __restrict__ W2, const float* __restrict__ b2,
    float* __restrict__ out)
{
  // bf16 tables, row stride 40 shorts (80 B): 16B-aligned chunks, rows spread
  // over all 8 bank-group positions ((5r+q) mod 8 with 5 coprime to 8).
  __shared__ alignas(16) unsigned short tab[3 * 128 * 40]; // 30720 B

  // Stage: convert fp32 lines -> bf16(rn) directly into LDS. Chunk c maps
  // linearly: LDS uint4 index c == table d*640 + row*5 + sub, sub 4 = pad.
  for (int c = threadIdx.x; c < 1920; c += TB) {
    int d   = c / 640;
    int rem = c - d * 640;
    int r   = rem / 5;
    int s   = rem - r * 5;
    uint4 o = make_uint4(0u, 0u, 0u, 0u);
    if (s < 4) {
      const float4* src = (const float4*)(lines + d * 4096 + r * 32 + s * 8);
      float4 f0 = src[0], f1 = src[1];
      o.x = pk2rn(f0.x, f0.y);
      o.y = pk2rn(f0.z, f0.w);
      o.z = pk2rn(f1.x, f1.y);
      o.w = pk2rn(f1.z, f1.w);
    }
    ((uint4*)tab)[c] = o;
  }

  const int lane = threadIdx.x & 63;
  const int wv   = threadIdx.x >> 6;
  const int col  = lane & 15;   // A-row m / C-col index
  const int q    = lane >> 4;   // quad: A k-octet / C row-group

  // Register-resident W1 B-fragments: lane holds W1[col+16t][q*8 .. q*8+7]
  bf16x8 bfrag[8];
  #pragma unroll
  for (int t = 0; t < 8; ++t) {
    const float4* wr = (const float4*)(W1 + (col + 16 * t) * 32 + q * 8);
    float4 w0 = wr[0], w1 = wr[1];
    union { uint4 u; bf16x8 v; } cv;
    cv.u.x = pk2rn(w0.x, w0.y);
    cv.u.y = pk2rn(w0.z, w0.w);
    cv.u.z = pk2rn(w1.x, w1.y);
    cv.u.w = pk2rn(w1.z, w1.w);
    bfrag[t] = cv.v;
  }
  float b1s[8], w2s[8];
  #pragma unroll
  for (int t = 0; t < 8; ++t) {
    b1s[t] = b1[col + 16 * t];   // channel of acc c[t] is col + 16t
    w2s[t] = W2[col + 16 * t];
  }
  const float vb2 = b2[0];
  __syncthreads();

  const char* tbase = (const char*)tab + q * 16; // this lane's 16B chunk in a row
  const int wave_base = blockIdx.x * PTS_PER_BLOCK + wv * (GROUPS * 16);

  // coord prefetch for group 0
  const float* cp0 = coords + (wave_base + col) * 3;
  float ncx = cp0[0], ncy = cp0[1], ncz = cp0[2];

  #pragma unroll 1
  for (int g = 0; g < GROUPS; ++g) {
    const int p0 = wave_base + g * 16;
    const float cx = ncx, cy = ncy, cz = ncz;
    if (g + 1 < GROUPS) {   // prefetch next group's coords
      const float* np = coords + (p0 + 16 + col) * 3;
      ncx = np[0]; ncy = np[1]; ncz = np[2];
    }

    // align_corners bilinear setup; coords in [-1,1) so both taps in range
    const float posx = (cx + 1.0f) * 63.5f;
    const float posy = (cy + 1.0f) * 63.5f;
    const float posz = (cz + 1.0f) * 63.5f;
    const int ix = (int)posx;
    const int iy = (int)posy;
    const int iz = (int)posz;
    const float frx = posx - (float)ix;
    const float fry = posy - (float)iy;
    const float frz = posz - (float)iz;

    const uint4* gx = (const uint4*)(tbase + ix * 80);
    const uint4* gy = (const uint4*)(tbase + 10240 + iy * 80);
    const uint4* gz = (const uint4*)(tbase + 20480 + iz * 80);
    const uint4 x0 = gx[0], x1 = gx[5];   // +5 uint4 = +80 B = next row
    const uint4 y0 = gy[0], y1 = gy[5];
    const uint4 z0 = gz[0], z1 = gz[5];

    const unsigned int X0[4] = {x0.x, x0.y, x0.z, x0.w};
    const unsigned int X1[4] = {x1.x, x1.y, x1.z, x1.w};
    const unsigned int Y0[4] = {y0.x, y0.y, y0.z, y0.w};
    const unsigned int Y1[4] = {y1.x, y1.y, y1.z, y1.w};
    const unsigned int Z0[4] = {z0.x, z0.y, z0.z, z0.w};
    const unsigned int Z1[4] = {z1.x, z1.y, z1.z, z1.w};

    const f32x2 fx = {frx, frx}, fy = {fry, fry}, fz = {frz, frz};
    unsigned int au[4];
    #pragma unroll
    for (int k = 0; k < 4; ++k) {
      f32x2 xa = unpk(X0[k]), xb = unpk(X1[k]);
      f32x2 ya = unpk(Y0[k]), yb = unpk(Y1[k]);
      f32x2 za = unpk(Z0[k]), zb = unpk(Z1[k]);
      f32x2 xe = xa + fx * (xb - xa);
      f32x2 ye = ya + fy * (yb - ya);
      f32x2 ze = za + fz * (zb - za);
      f32x2 t   = xe + ye;
      f32x2 s1  = t + ze;
      f32x2 xy  = xe * ye;
      f32x2 pr  = ze * t + xy;       // xy + xz + yz
      f32x2 xyz = xy * ze;
      f32x2 f   = s1 + pr * 2.5f;    // 1/RANGE
      f = f + xyz * 6.25f;           // 1/RANGE^2
      // pack 2 channels: truncate both floats to bf16 in one v_perm
      au[k] = __builtin_amdgcn_perm(__float_as_uint(f.y), __float_as_uint(f.x),
                                    0x07060302u);
    }
    union { uint4 u; bf16x8 v; } av;
    av.u = make_uint4(au[0], au[1], au[2], au[3]);

    const f32x4 z4 = {0.f, 0.f, 0.f, 0.f};
    f32x4 c[8];
    #pragma unroll
    for (int t = 0; t < 8; ++t)
      c[t] = __builtin_amdgcn_mfma_f32_16x16x32_bf16(av.v, bfrag[t], z4, 0, 0, 0);

    // epilogue: relu(h+b1).W2 — pair over C rows (adjacent acc regs -> pk ops)
    f32x2 a01 = {0.f, 0.f}, a23 = {0.f, 0.f};
    #pragma unroll
    for (int t = 0; t < 8; ++t) {
      f32x2 h01 = c[t].xy + b1s[t];
      f32x2 h23 = c[t].zw + b1s[t];
      h01 = __builtin_elementwise_max(h01, (f32x2){0.f, 0.f});
      h23 = __builtin_elementwise_max(h23, (f32x2){0.f, 0.f});
      a01 += h01 * w2s[t];
      a23 += h23 * w2s[t];
    }
    // reduce over the 16 col-lanes with DPP row_shr (VALU only, sum -> lane 15)
    float s0 = a01.x, s1v = a01.y, s2 = a23.x, s3 = a23.y;
    s0  = dpp_add<0x118>(dpp_add<0x114>(dpp_add<0x112>(dpp_add<0x111>(s0))));
    s1v = dpp_add<0x118>(dpp_add<0x114>(dpp_add<0x112>(dpp_add<0x111>(s1v))));
    s2  = dpp_add<0x118>(dpp_add<0x114>(dpp_add<0x112>(dpp_add<0x111>(s2))));
    s3  = dpp_add<0x118>(dpp_add<0x114>(dpp_add<0x112>(dpp_add<0x111>(s3))));
    if (col == 15) {   // lane 15 of quad q stores points p0 + q*4 .. +3
      float4 o = make_float4(s0 + vb2, s1v + vb2, s2 + vb2, s3 + vb2);
      *((float4*)(out + p0 + q * 4)) = o;
    }
  }
}

extern "C" void kernel_launch(void* const* d_in, const int* in_sizes, int n_in,
                              void* d_out, int out_size, void* d_ws, size_t ws_size,
                              hipStream_t stream) {
  const float* coords = (const float*)d_in[0];
  const float* lines  = (const float*)d_in[1];
  const float* W1     = (const float*)d_in[2];
  const float* b1     = (const float*)d_in[3];
  const float* W2     = (const float*)d_in[4];
  const float* b2     = (const float*)d_in[5];
  float* out = (float*)d_out;
  const int M = in_sizes[0] / 3;

  const int blocks = (M + PTS_PER_BLOCK - 1) / PTS_PER_BLOCK;
  fused_kernel<<<blocks, TB, 0, stream>>>(coords, lines, W1, b1, W2, b2, out);
}

// Round 4
// 107.537 us; speedup vs baseline: 1.2490x; 1.2490x over previous
//
#include <hip/hip_runtime.h>

typedef _Float16 h2 __attribute__((ext_vector_type(2)));
typedef _Float16 h8 __attribute__((ext_vector_type(8)));
typedef __fp16 fp16x2 __attribute__((ext_vector_type(2)));
typedef float f32x4 __attribute__((ext_vector_type(4)));
typedef float f32x2 __attribute__((ext_vector_type(2)));

#define TB 512
#define GROUPS 8
#define WAVES (TB / 64)
#define PTS_PER_BLOCK (WAVES * GROUPS * 16)   // 1024

// pack two f32 -> two f16 (RTZ) in one v_cvt_pkrtz_f16_f32; return raw bits
__device__ __forceinline__ unsigned int pkh(float a, float b) {
  union { fp16x2 h; unsigned int u; } cv;
  cv.h = __builtin_amdgcn_cvt_pkrtz(a, b);
  return cv.u;
}
__device__ __forceinline__ h2 h2cast(unsigned int u) {
  union { unsigned int u; h2 h; } cv;
  cv.u = u;
  return cv.h;
}
// v_add with DPP row_shr:N (reduce within each 16-lane row, sum -> lane 15)
template <int CTRL>
__device__ __forceinline__ float dpp_add(float v) {
  return v + __int_as_float(
                 __builtin_amdgcn_update_dpp(0, __float_as_int(v), CTRL, 0xf, 0xf, true));
}

__global__ __launch_bounds__(TB) void fused_kernel(
    const float* __restrict__ coords, const float* __restrict__ lines,
    const float* __restrict__ W1, const float* __restrict__ b1,
    const float* __restrict__ W2, const float* __restrict__ b2,
    float* __restrict__ out)
{
  // fp16 tables, row stride 40 halves (80 B): 16B-aligned chunks, rows spread
  // over all 8 bank-group positions ((5r+q) mod 8, 5 coprime to 8).
  __shared__ alignas(16) unsigned short tab[3 * 128 * 40]; // 30720 B

  // Stage: fp32 lines -> fp16 directly into LDS. uint4 chunk c = d*640 + r*5 + s.
  for (int c = threadIdx.x; c < 1920; c += TB) {
    int d   = c / 640;
    int rem = c - d * 640;
    int r   = rem / 5;
    int s   = rem - r * 5;
    uint4 o = make_uint4(0u, 0u, 0u, 0u);
    if (s < 4) {
      const float4* src = (const float4*)(lines + d * 4096 + r * 32 + s * 8);
      float4 f0 = src[0], f1 = src[1];
      o.x = pkh(f0.x, f0.y);
      o.y = pkh(f0.z, f0.w);
      o.z = pkh(f1.x, f1.y);
      o.w = pkh(f1.z, f1.w);
    }
    ((uint4*)tab)[c] = o;
  }

  const int lane = threadIdx.x & 63;
  const int wv   = threadIdx.x >> 6;
  const int col  = lane & 15;   // A-row m (point) / C-col n (hidden unit)
  const int q    = lane >> 4;   // quad: A k-octet / C row-group

  // Register-resident W1 B-fragments (fp16): lane holds W1[col+16t][q*8..q*8+7]
  h8 bfrag[8];
  #pragma unroll
  for (int t = 0; t < 8; ++t) {
    const float4* wr = (const float4*)(W1 + (col + 16 * t) * 32 + q * 8);
    float4 w0 = wr[0], w1 = wr[1];
    union { uint4 u; h8 v; } cv;
    cv.u.x = pkh(w0.x, w0.y);
    cv.u.y = pkh(w0.z, w0.w);
    cv.u.z = pkh(w1.x, w1.y);
    cv.u.w = pkh(w1.z, w1.w);
    bfrag[t] = cv.v;
  }
  float b1s[8], w2s[8];
  #pragma unroll
  for (int t = 0; t < 8; ++t) {
    b1s[t] = b1[col + 16 * t];   // hidden unit of acc tile t is col + 16t
    w2s[t] = W2[col + 16 * t];
  }
  const float vb2 = b2[0];
  __syncthreads();

  const char* tbase = (const char*)tab + q * 16; // lane's 16B chunk in a row
  const int wave_base = blockIdx.x * PTS_PER_BLOCK + wv * (GROUPS * 16);

  // coord prefetch for group 0
  const float* cp0 = coords + (wave_base + col) * 3;
  float ncx = cp0[0], ncy = cp0[1], ncz = cp0[2];

  #pragma unroll 1
  for (int g = 0; g < GROUPS; ++g) {
    const int p0 = wave_base + g * 16;
    const float cx = ncx, cy = ncy, cz = ncz;
    if (g + 1 < GROUPS) {   // prefetch next group's coords
      const float* np = coords + (p0 + 16 + col) * 3;
      ncx = np[0]; ncy = np[1]; ncz = np[2];
    }

    // align_corners bilinear setup (coords in [-1,1) so both taps in range)
    const float posx = (cx + 1.0f) * 63.5f;
    const float posy = (cy + 1.0f) * 63.5f;
    const float posz = (cz + 1.0f) * 63.5f;
    const int ix = (int)posx;
    const int iy = (int)posy;
    const int iz = (int)posz;
    const float frx = posx - (float)ix;
    const float fry = posy - (float)iy;
    const float frz = posz - (float)iz;

    const uint4* gx = (const uint4*)(tbase + ix * 80);
    const uint4* gy = (const uint4*)(tbase + 10240 + iy * 80);
    const uint4* gz = (const uint4*)(tbase + 20480 + iz * 80);
    union { uint4 u; h2 h[4]; } X0, X1, Y0, Y1, Z0, Z1;
    X0.u = gx[0]; X1.u = gx[5];   // +5 uint4 = +80 B = next row
    Y0.u = gy[0]; Y1.u = gy[5];
    Z0.u = gz[0]; Z1.u = gz[5];

    // frac as packed fp16 (frac in [0,1): fp16 error ~5e-4, fine)
    const h2 fx = h2cast(pkh(frx, frx));
    const h2 fy = h2cast(pkh(fry, fry));
    const h2 fz = h2cast(pkh(frz, frz));
    const h2 C1 = {(_Float16)2.5f, (_Float16)2.5f};    // 1/RANGE (exact)
    const h2 C2 = {(_Float16)6.25f, (_Float16)6.25f};  // 1/RANGE^2 (exact)

    union { h8 v; h2 h[4]; } av;
    #pragma unroll
    for (int k = 0; k < 4; ++k) {
      h2 xa = X0.h[k], xb = X1.h[k];
      h2 ya = Y0.h[k], yb = Y1.h[k];
      h2 za = Z0.h[k], zb = Z1.h[k];
      h2 xe = xa + fx * (xb - xa);     // v_pk_add/sub/fma_f16: 2 ch per instr
      h2 ye = ya + fy * (yb - ya);
      h2 ze = za + fz * (zb - za);
      h2 t   = xe + ye;
      h2 s1  = t + ze;
      h2 xy  = xe * ye;
      h2 pr  = ze * t + xy;            // xy + xz + yz
      h2 xyz = xy * ze;
      h2 f   = s1 + pr * C1;
      f = f + xyz * C2;
      av.h[k] = f;                     // already in A-fragment layout
    }

    // MFMA + fused epilogue: relu(h+b1).W2 accumulated per tile t
    const f32x4 z4 = {0.f, 0.f, 0.f, 0.f};
    f32x2 a01 = {0.f, 0.f}, a23 = {0.f, 0.f};
    #pragma unroll
    for (int t = 0; t < 8; ++t) {
      f32x4 c = __builtin_amdgcn_mfma_f32_16x16x32_f16(av.v, bfrag[t], z4, 0, 0, 0);
      f32x2 h01 = c.xy + b1s[t];
      f32x2 h23 = c.zw + b1s[t];
      h01 = __builtin_elementwise_max(h01, (f32x2){0.f, 0.f});
      h23 = __builtin_elementwise_max(h23, (f32x2){0.f, 0.f});
      a01 += h01 * w2s[t];
      a23 += h23 * w2s[t];
    }

    // reduce over the 16 col-lanes with DPP row_shr (VALU only, sum -> lane 15)
    float s0 = a01.x, s1v = a01.y, s2 = a23.x, s3 = a23.y;
    s0  = dpp_add<0x118>(dpp_add<0x114>(dpp_add<0x112>(dpp_add<0x111>(s0))));
    s1v = dpp_add<0x118>(dpp_add<0x114>(dpp_add<0x112>(dpp_add<0x111>(s1v))));
    s2  = dpp_add<0x118>(dpp_add<0x114>(dpp_add<0x112>(dpp_add<0x111>(s2))));
    s3  = dpp_add<0x118>(dpp_add<0x114>(dpp_add<0x112>(dpp_add<0x111>(s3))));
    if (col == 15) {   // lane 15 of quad q stores points p0 + q*4 .. +3
      float4 o = make_float4(s0 + vb2, s1v + vb2, s2 + vb2, s3 + vb2);
      *((float4*)(out + p0 + q * 4)) = o;
    }
  }
}

extern "C" void kernel_launch(void* const* d_in, const int* in_sizes, int n_in,
                              void* d_out, int out_size, void* d_ws, size_t ws_size,
                              hipStream_t stream) {
  const float* coords = (const float*)d_in[0];
  const float* lines  = (const float*)d_in[1];
  const float* W1     = (const float*)d_in[2];
  const float* b1     = (const float*)d_in[3];
  const float* W2     = (const float*)d_in[4];
  const float* b2     = (const float*)d_in[5];
  float* out = (float*)d_out;
  const int M = in_sizes[0] / 3;

  const int blocks = (M + PTS_PER_BLOCK - 1) / PTS_PER_BLOCK;
  fused_kernel<<<blocks, TB, 0, stream>>>(coords, lines, W1, b1, W2, b2, out);
}